// Round 14
// baseline (141.652 us; speedup 1.0000x reference)
//
#include <hip/hip_runtime.h>

typedef _Float16 f16;
typedef f16 f16x2 __attribute__((ext_vector_type(2)));
typedef f16 f16x4 __attribute__((ext_vector_type(4)));
typedef f16 f16x8 __attribute__((ext_vector_type(8)));
typedef float f32x4 __attribute__((ext_vector_type(4)));

static constexpr int S_LEN  = 2048;
static constexpr int D_DIM  = 64;
static constexpr int NTILE  = 64;     // keys per k-tile
static constexpr float SCALE_LOG2E = 0.1803368801111204f; // (1/sqrt(64))*log2(e)

#define MFMA32(a,b,c) __builtin_amdgcn_mfma_f32_16x16x32_f16((a),(b),(c),0,0,0)
// NOTE: legacy K=16 shape has no underscore before f16 on gfx950
#define MFMA16(a,b,c) __builtin_amdgcn_mfma_f32_16x16x16f16((a),(b),(c),0,0,0)

// ============================ pre-pass ====================================
// Packs K and V to f16 in d_ws in REGISTER-FRAGMENT order (r13 layout,
// unchanged values):
//   Kf[head][tile][cK][lane][8]: cK=(j>>4)*2+(c>>2), lane=(c&3)*16+(j&15)
//   Vf[head][tile][cV][lane][8]: cV=(d>>4)*2+(cl&1), lane=(cl>>1)*16+(d&15),
//       slot s -> V[tile*64 + j(cl,s)][d],
//       j(cl,s) = (cl&1)*32 + (s>>2)*16 + ((cl>>1)&3)*4 + (s&3)
// r14: V inner loop vectorized — thread owns a d-PAIR x one j-chunk: 8x
// float2 LDS reads produce 2 outputs (was 16 scalar reads) -> ~2x fewer,
// 2x wider LDS ops. r13 prepack measured 13.3us vs 7.6us BW floor.
__global__ __launch_bounds__(256)
void prepack(const float* __restrict__ kg, const float* __restrict__ vg,
             f16* __restrict__ kp, f16* __restrict__ vp) {
  int b = blockIdx.x;
  const bool isV = (b >= 1024);
  if (isV) b -= 1024;
  const int head = b >> 5;   // 0..31
  const int tile = b & 31;   // 0..31
  const int t = threadIdx.x;
  const size_t base = ((size_t)head * S_LEN + (size_t)tile * NTILE) * D_DIM;

  if (!isV) {
    const float* src = kg + base;
    f16* dst = kp + base;
#pragma unroll
    for (int e = 0; e < 2; ++e) {
      const int ch = e * 256 + t;      // lane-contiguous: loads fully coalesced
      const int j = ch >> 3, c = ch & 7;   // row j, d-chunk c
      const float* s = src + (size_t)ch * 8;   // == j*64 + c*8
      float4 a0 = *(const float4*)s;
      float4 a1 = *(const float4*)(s + 4);
      f16x8 o;
      o[0] = (f16)a0.x; o[1] = (f16)a0.y; o[2] = (f16)a0.z; o[3] = (f16)a0.w;
      o[4] = (f16)a1.x; o[5] = (f16)a1.y; o[6] = (f16)a1.z; o[7] = (f16)a1.w;
      const int cK    = (j >> 4) * 2 + (c >> 2);
      const int lanei = (c & 3) * 16 + (j & 15);
      *(f16x8*)(dst + (cK * 64 + lanei) * 8) = o;
    }
  } else {
    __shared__ float ldsv[64 * 68];    // [j][d], pad 68 keeps alignment
    const float* src = vg + base;
#pragma unroll
    for (int i = 0; i < 4; ++i) {
      const int row = t >> 2, col = (t & 3) * 16 + i * 4;
      *(float4*)&ldsv[row * 68 + col] = *(const float4*)(src + row * 64 + col);
    }
    __syncthreads();
    f16* dst = vp + base;
    const int d0 = (t >> 3) * 2;       // even d of the pair
    const int cl = t & 7;              // j-chunk
    f16x8 o0, o1;
#pragma unroll
    for (int s = 0; s < 8; ++s) {
      const int j = (cl & 1) * 32 + (s >> 2) * 16 + ((cl >> 1) & 3) * 4 + (s & 3);
      const float2 v2 = *(const float2*)&ldsv[j * 68 + d0];   // 8B-aligned
      o0[s] = (f16)v2.x; o1[s] = (f16)v2.y;
    }
    {
      const int cV0 = (d0 >> 4) * 2 + (cl & 1);
      const int li0 = (cl >> 1) * 16 + (d0 & 15);
      *(f16x8*)(dst + (cV0 * 64 + li0) * 8) = o0;
      const int d1 = d0 + 1;
      const int cV1 = (d1 >> 4) * 2 + (cl & 1);
      const int li1 = (cl >> 1) * 16 + (d1 & 15);
      *(f16x8*)(dst + (cV1 * 64 + li1) * 8) = o1;
    }
  }
}

// ====================== main kernel (r14: zero-LDS + dbuf V) ==============
// r13 post-mortem: zero-LDS main = 54.4us, still latency-bound at 2 waves/
// SIMD (L1-BW caps more waves). r14: double-buffer V fragments (named vfA/
// vfB, rule #20) and issue V(t+1) right after K(t+1) — V-wait gap grows from
// ~QK+exp2 (~250-400cyc, marginal vs ~200-300cyc L2 latency) to the whole
// exp2+PV+QK span. K keeps single buffer (gap already a full phase).
__global__ __launch_bounds__(256, 2)
void attn_pp(const float* __restrict__ qg, const f16* __restrict__ kp,
             const f16* __restrict__ vp, float* __restrict__ og) {
  // head-clustered XCD swizzle (r3): each XCD owns 4 whole heads
  const int xcd  = blockIdx.x & 7;
  const int slot = blockIdx.x >> 3;
  const int bh   = xcd * 4 + (slot >> 4);
  const int qt   = slot & 15;
  const size_t hbase = (size_t)bh * S_LEN * D_DIM;
  const float* qh = qg + hbase;
  const f16*   kh = kp + hbase;
  const f16*   vh = vp + hbase;
  float*       oh = og + hbase;

  const int tid  = threadIdx.x;
  const int wave = tid >> 6;
  const int lane = tid & 63;
  const int L    = lane & 15;
  const int quad = lane >> 4;

  // ---- Q fragments, pre-scaled by SCALE_LOG2E (r12) ----
  f16x8 qf[2][2];
  const int qrow0 = qt * 128 + wave * 32;
#pragma unroll
  for (int qs = 0; qs < 2; ++qs)
#pragma unroll
    for (int kc = 0; kc < 2; ++kc) {
      const float* src = qh + (size_t)(qrow0 + qs * 16 + L) * D_DIM + kc * 32 + quad * 8;
      float4 x0 = *(const float4*)src;
      float4 x1 = *(const float4*)(src + 4);
      f16x8 t;
      t[0] = (f16)(x0.x * SCALE_LOG2E); t[1] = (f16)(x0.y * SCALE_LOG2E);
      t[2] = (f16)(x0.z * SCALE_LOG2E); t[3] = (f16)(x0.w * SCALE_LOG2E);
      t[4] = (f16)(x1.x * SCALE_LOG2E); t[5] = (f16)(x1.y * SCALE_LOG2E);
      t[6] = (f16)(x1.z * SCALE_LOG2E); t[7] = (f16)(x1.w * SCALE_LOG2E);
      qf[qs][kc] = t;
    }

  f32x4 oacc[2][4];
#pragma unroll
  for (int qs = 0; qs < 2; ++qs)
#pragma unroll
    for (int dt = 0; dt < 4; ++dt) oacc[qs][dt] = (f32x4){0.f, 0.f, 0.f, 0.f};
  float lsum[2] = {0.f, 0.f};

  f16x8 kf[8], vfA[8], vfB[8];
#define LOADK(t_)                                                          \
  do {                                                                     \
    const f16* p = kh + (size_t)(t_) * 4096 + lane * 8;                    \
    _Pragma("unroll")                                                      \
    for (int c = 0; c < 8; ++c) kf[c] = *(const f16x8*)(p + c * 512);      \
  } while (0)
#define LOADV(buf, t_)                                                     \
  do {                                                                     \
    const f16* p = vh + (size_t)(t_) * 4096 + lane * 8;                    \
    _Pragma("unroll")                                                      \
    for (int c = 0; c < 8; ++c) buf[c] = *(const f16x8*)(p + c * 512);     \
  } while (0)

  // ---- compute phases (inlined lambdas; static indexing everywhere) ----
  auto qk_phase = [&](f32x4 (&sfr)[2][4]) {
#pragma unroll
    for (int qs = 0; qs < 2; ++qs)
#pragma unroll
      for (int jt = 0; jt < 4; ++jt) sfr[qs][jt] = (f32x4){0.f, 0.f, 0.f, 0.f};
#pragma unroll
    for (int jt = 0; jt < 4; ++jt)
#pragma unroll
      for (int kc = 0; kc < 2; ++kc) {
        const f16x8 af = kf[jt * 2 + kc];
        sfr[0][jt] = MFMA32(af, qf[0][kc], sfr[0][jt]);
        sfr[1][jt] = MFMA32(af, qf[1][kc], sfr[1][jt]);
      }
  };
  auto sm_phase = [&](f32x4 (&sfr)[2][4], f16x4 (&pf)[2][4]) {
#pragma unroll
    for (int qs = 0; qs < 2; ++qs)
#pragma unroll
      for (int jt = 0; jt < 4; ++jt) {
#pragma unroll
        for (int r = 0; r < 4; ++r)
          pf[qs][jt][r] = (f16)__builtin_amdgcn_exp2f(sfr[qs][jt][r]);
#if __has_builtin(__builtin_amdgcn_fdot2)
        const f16x2 one2 = {(f16)1.f, (f16)1.f};
        f16x2 plo = {pf[qs][jt][0], pf[qs][jt][1]};
        f16x2 phi = {pf[qs][jt][2], pf[qs][jt][3]};
        lsum[qs] = __builtin_amdgcn_fdot2(plo, one2, lsum[qs], false);
        lsum[qs] = __builtin_amdgcn_fdot2(phi, one2, lsum[qs], false);
#else
#pragma unroll
        for (int r = 0; r < 4; ++r) lsum[qs] += (float)pf[qs][jt][r];
#endif
      }
  };
  auto pv_phase = [&](f16x4 (&pf)[2][4], f16x8 (&vf)[8]) {
#pragma unroll
    for (int jtp = 0; jtp < 2; ++jtp)
#pragma unroll
      for (int dt = 0; dt < 4; ++dt) {
        const f16x8 vv = vf[dt * 2 + jtp];
        f16x4 vlo = {vv[0], vv[1], vv[2], vv[3]};
        f16x4 vhi = {vv[4], vv[5], vv[6], vv[7]};
        oacc[0][dt] = MFMA16(pf[0][jtp * 2],     vlo, oacc[0][dt]);
        oacc[0][dt] = MFMA16(pf[0][jtp * 2 + 1], vhi, oacc[0][dt]);
        oacc[1][dt] = MFMA16(pf[1][jtp * 2],     vlo, oacc[1][dt]);
        oacc[1][dt] = MFMA16(pf[1][jtp * 2 + 1], vhi, oacc[1][dt]);
      }
  };

  constexpr int NT = S_LEN / NTILE;   // 32 (even)
  LOADK(0);
  LOADV(vfA, 0);

  for (int p = 0; p < NT / 2; ++p) {
    const int t1 = 2 * p + 1;
    {  // ---- tile 2p: V in vfA ----
      f32x4 sfr[2][4]; f16x4 pf[2][4];
      qk_phase(sfr);          // consumes kf(2p)
      LOADK(t1);              // K for tile 2p+1
      LOADV(vfB, t1);         // V for tile 2p+1 — issued EARLY (r14)
      sm_phase(sfr, pf);
      pv_phase(pf, vfA);
    }
    {  // ---- tile 2p+1: V in vfB ----
      f32x4 sfr[2][4]; f16x4 pf[2][4];
      qk_phase(sfr);          // consumes kf(2p+1)
      if (t1 + 1 < NT) {
        LOADK(t1 + 1);
        LOADV(vfA, t1 + 1);
      }
      sm_phase(sfr, pf);
      pv_phase(pf, vfB);
    }
  }
#undef LOADK
#undef LOADV

  // ---- epilogue: reduce l across quads, redistribute, store ----
#pragma unroll
  for (int qs = 0; qs < 2; ++qs) {
    float l = lsum[qs];
    l += __shfl_xor(l, 16);
    l += __shfl_xor(l, 32);
#pragma unroll
    for (int r = 0; r < 4; ++r) {
      const float inv = 1.0f / __shfl(l, quad * 4 + r);
      float* dst = oh + (size_t)(qrow0 + qs * 16 + quad * 4 + r) * D_DIM + L;
#pragma unroll
      for (int dt = 0; dt < 4; ++dt)
        dst[dt * 16] = oacc[qs][dt][r] * inv;
    }
  }
}

// ================= fallback: r7 kernel (no workspace needed) ==============
static constexpr int MBLOCK = 128;
static constexpr int KST = 72;
static constexpr int VST = 72;
static constexpr float FB_SCALE_LOG2E = 0.1803368801111204f;
static constexpr float FB_SHIFT = 4.0f;

__global__ __launch_bounds__(256, 2)
void attn_fwd_fb(const float* __restrict__ qg, const float* __restrict__ kg,
                 const float* __restrict__ vg, float* __restrict__ og) {
  const int xcd  = blockIdx.x & 7;
  const int slot = blockIdx.x >> 3;
  const int bh   = xcd * 4 + (slot >> 4);
  const int qt   = slot & 15;
  const size_t hbase = (size_t)bh * S_LEN * D_DIM;
  const float* qh = qg + hbase;
  const float* kh = kg + hbase;
  const float* vh = vg + hbase;
  float*       oh = og + hbase;

  const int tid  = threadIdx.x;
  const int wave = tid >> 6;
  const int lane = tid & 63;
  const int L    = lane & 15;
  const int quad = lane >> 4;
  const int lhalf = L >> 3;

  __shared__ f16 Ks[2][NTILE * KST];
  __shared__ f16 Vt[2][D_DIM * VST];

  f16x8 qf[2][2];
  const int qrow0 = qt * MBLOCK + wave * 32;
#pragma unroll
  for (int qs = 0; qs < 2; ++qs)
#pragma unroll
    for (int kc = 0; kc < 2; ++kc) {
      const float* src = qh + (size_t)(qrow0 + qs * 16 + L) * D_DIM + kc * 32 + quad * 8;
      float4 x0 = *(const float4*)src;
      float4 x1 = *(const float4*)(src + 4);
      f16x8 t;
      t[0] = (f16)x0.x; t[1] = (f16)x0.y; t[2] = (f16)x0.z; t[3] = (f16)x0.w;
      t[4] = (f16)x1.x; t[5] = (f16)x1.y; t[6] = (f16)x1.z; t[7] = (f16)x1.w;
      qf[qs][kc] = t;
    }

  f32x4 oacc[2][4];
#pragma unroll
  for (int qs = 0; qs < 2; ++qs)
#pragma unroll
    for (int dt = 0; dt < 4; ++dt) oacc[qs][dt] = (f32x4){0.f, 0.f, 0.f, 0.f};
  float lsum[2] = {0.f, 0.f};

  const int sj  = tid >> 2, sc  = tid & 3;
  const int jd  = tid >> 4, dcc = tid & 15;
  const int vpos = ((jd & 3) * 4 + (jd >> 2)) * 4;
  const int xorv = (dcc >> 1) << 3;
  const float* kstage = kh + (size_t)sj * D_DIM + sc * 4;
  const float* vstage = vh + (size_t)(jd * 4) * D_DIM + dcc * 4;

  float4 kreg[4], vreg[4];
#pragma unroll
  for (int i = 0; i < 4; ++i) {
    kreg[i] = *(const float4*)(kstage + i * 16);
    vreg[i] = *(const float4*)(vstage + (size_t)i * D_DIM);
  }
#pragma unroll
  for (int i = 0; i < 4; ++i) {
    f16x4 t;
    t[0] = (f16)kreg[i].x; t[1] = (f16)kreg[i].y;
    t[2] = (f16)kreg[i].z; t[3] = (f16)kreg[i].w;
    *(f16x4*)&Ks[0][sj * KST + i * 16 + sc * 4] = t;
  }
  {
    const float* vr = reinterpret_cast<const float*>(vreg);
#pragma unroll
    for (int c = 0; c < 4; ++c) {
      f16x4 t;
      t[0] = (f16)vr[0 * 4 + c]; t[1] = (f16)vr[1 * 4 + c];
      t[2] = (f16)vr[2 * 4 + c]; t[3] = (f16)vr[3 * 4 + c];
      *(f16x4*)&Vt[0][(dcc * 4 + c) * VST + (vpos ^ xorv)] = t;
    }
  }
#pragma unroll
  for (int i = 0; i < 4; ++i) {
    kreg[i] = *(const float4*)(kstage + (size_t)1 * NTILE * D_DIM + i * 16);
    vreg[i] = *(const float4*)(vstage + (size_t)1 * NTILE * D_DIM + (size_t)i * D_DIM);
  }
  __syncthreads();

  constexpr int NT = S_LEN / NTILE;
  for (int kt = 0; kt < NT; ++kt) {
    const int cur = kt & 1;
    const int nxt = cur ^ 1;

    f32x4 sfr[2][4];
#pragma unroll
    for (int qs = 0; qs < 2; ++qs)
#pragma unroll
      for (int jt = 0; jt < 4; ++jt) sfr[qs][jt] = (f32x4){0.f, 0.f, 0.f, 0.f};
#pragma unroll
    for (int jt = 0; jt < 4; ++jt)
#pragma unroll
      for (int kc = 0; kc < 2; ++kc) {
        f16x8 af = *(const f16x8*)&Ks[cur][(jt * 16 + L) * KST + kc * 32 + quad * 8];
        sfr[0][jt] = MFMA32(af, qf[0][kc], sfr[0][jt]);
        sfr[1][jt] = MFMA32(af, qf[1][kc], sfr[1][jt]);
      }

    if (kt + 1 < NT) {
#pragma unroll
      for (int i = 0; i < 4; ++i) {
        f16x4 t;
        t[0] = (f16)kreg[i].x; t[1] = (f16)kreg[i].y;
        t[2] = (f16)kreg[i].z; t[3] = (f16)kreg[i].w;
        *(f16x4*)&Ks[nxt][sj * KST + i * 16 + sc * 4] = t;
      }
      const float* vr = reinterpret_cast<const float*>(vreg);
#pragma unroll
      for (int c = 0; c < 4; ++c) {
        f16x4 t;
        t[0] = (f16)vr[0 * 4 + c]; t[1] = (f16)vr[1 * 4 + c];
        t[2] = (f16)vr[2 * 4 + c]; t[3] = (f16)vr[3 * 4 + c];
        *(f16x4*)&Vt[nxt][(dcc * 4 + c) * VST + (vpos ^ xorv)] = t;
      }
    }
    if (kt + 2 < NT) {
      const float* kpp = kstage + (size_t)(kt + 2) * NTILE * D_DIM;
      const float* vpp = vstage + (size_t)(kt + 2) * NTILE * D_DIM;
#pragma unroll
      for (int i = 0; i < 4; ++i) {
        kreg[i] = *(const float4*)(kpp + i * 16);
        vreg[i] = *(const float4*)(vpp + (size_t)i * D_DIM);
      }
    }

    f16x4 pf[2][4];
#pragma unroll
    for (int qs = 0; qs < 2; ++qs)
#pragma unroll
      for (int jt = 0; jt < 4; ++jt) {
#pragma unroll
        for (int r = 0; r < 4; ++r) {
          const float p = __builtin_amdgcn_exp2f(
              __builtin_fmaf(sfr[qs][jt][r], FB_SCALE_LOG2E, -FB_SHIFT));
          lsum[qs] += p;
          pf[qs][jt][r] = (f16)p;
        }
      }

#pragma unroll
    for (int jtp = 0; jtp < 2; ++jtp)
#pragma unroll
      for (int dt = 0; dt < 4; ++dt) {
        const int xorr = ((2 * dt + lhalf) & 7) << 3;
        f16x8 vf = *(const f16x8*)&Vt[cur][(dt * 16 + L) * VST +
                                          ((quad * 16 + jtp * 8) ^ xorr)];
        f16x4 vlo = {vf[0], vf[1], vf[2], vf[3]};
        f16x4 vhi = {vf[4], vf[5], vf[6], vf[7]};
        oacc[0][dt] = MFMA16(pf[0][jtp * 2],     vlo, oacc[0][dt]);
        oacc[0][dt] = MFMA16(pf[0][jtp * 2 + 1], vhi, oacc[0][dt]);
        oacc[1][dt] = MFMA16(pf[1][jtp * 2],     vlo, oacc[1][dt]);
        oacc[1][dt] = MFMA16(pf[1][jtp * 2 + 1], vhi, oacc[1][dt]);
      }

    __syncthreads();
  }

#pragma unroll
  for (int qs = 0; qs < 2; ++qs) {
    float l = lsum[qs];
    l += __shfl_xor(l, 16);
    l += __shfl_xor(l, 32);
#pragma unroll
    for (int r = 0; r < 4; ++r) {
      const float inv = 1.0f / __shfl(l, quad * 4 + r);
      float* dst = oh + (size_t)(qrow0 + qs * 16 + quad * 4 + r) * D_DIM + L;
#pragma unroll
      for (int dt = 0; dt < 4; ++dt)
        dst[dt * 16] = oacc[qs][dt][r] * inv;
    }
  }
}

extern "C" void kernel_launch(void* const* d_in, const int* in_sizes, int n_in,
                              void* d_out, int out_size, void* d_ws, size_t ws_size,
                              hipStream_t stream) {
  const float* q = (const float*)d_in[0];
  const float* k = (const float*)d_in[1];
  const float* v = (const float*)d_in[2];
  float* o = (float*)d_out;

  const size_t kv_elems = (size_t)32 * S_LEN * D_DIM;       // 4.19e6 f16 each
  const size_t need = 2 * kv_elems * sizeof(f16);           // 16 MB

  if (ws_size >= need && d_ws != nullptr) {
    f16* kp = (f16*)d_ws;
    f16* vp = kp + kv_elems;
    prepack<<<dim3(2048), dim3(256), 0, stream>>>(k, v, kp, vp);
    attn_pp<<<dim3(512), dim3(256), 0, stream>>>(q, kp, vp, o);
  } else {
    attn_fwd_fb<<<dim3(512), dim3(256), 0, stream>>>(q, k, v, o);
  }
}

// Round 15
// 134.948 us; speedup vs baseline: 1.0497x; 1.0497x over previous
//
#include <hip/hip_runtime.h>

typedef _Float16 f16;
typedef f16 f16x2 __attribute__((ext_vector_type(2)));
typedef f16 f16x4 __attribute__((ext_vector_type(4)));
typedef f16 f16x8 __attribute__((ext_vector_type(8)));
typedef float f32x4 __attribute__((ext_vector_type(4)));

static constexpr int S_LEN  = 2048;
static constexpr int D_DIM  = 64;
static constexpr int NTILE  = 64;     // keys per k-tile
static constexpr float SCALE_LOG2E = 0.1803368801111204f; // (1/sqrt(64))*log2(e)

#define MFMA32(a,b,c) __builtin_amdgcn_mfma_f32_16x16x32_f16((a),(b),(c),0,0,0)
// NOTE: legacy K=16 shape has no underscore before f16 on gfx950
#define MFMA16(a,b,c) __builtin_amdgcn_mfma_f32_16x16x16f16((a),(b),(c),0,0,0)

// ============================ pre-pass (r14, kept: ~6.7us) ================
// Packs K and V to f16 in d_ws in REGISTER-FRAGMENT order:
//   Kf[head][tile][cK][lane][8]: cK=(j>>4)*2+(c>>2), lane=(c&3)*16+(j&15)
//   Vf[head][tile][cV][lane][8]: cV=(d>>4)*2+(cl&1), lane=(cl>>1)*16+(d&15),
//       slot s -> V[tile*64 + j(cl,s)][d],
//       j(cl,s) = (cl&1)*32 + (s>>2)*16 + ((cl>>1)&3)*4 + (s&3)
// V path: thread owns a d-PAIR x one j-chunk -> 8x float2 LDS reads per 2
// outputs (r14 vectorization: prepack 13.3 -> 6.7us, near BW floor).
__global__ __launch_bounds__(256)
void prepack(const float* __restrict__ kg, const float* __restrict__ vg,
             f16* __restrict__ kp, f16* __restrict__ vp) {
  int b = blockIdx.x;
  const bool isV = (b >= 1024);
  if (isV) b -= 1024;
  const int head = b >> 5;   // 0..31
  const int tile = b & 31;   // 0..31
  const int t = threadIdx.x;
  const size_t base = ((size_t)head * S_LEN + (size_t)tile * NTILE) * D_DIM;

  if (!isV) {
    const float* src = kg + base;
    f16* dst = kp + base;
#pragma unroll
    for (int e = 0; e < 2; ++e) {
      const int ch = e * 256 + t;      // lane-contiguous: loads fully coalesced
      const int j = ch >> 3, c = ch & 7;   // row j, d-chunk c
      const float* s = src + (size_t)ch * 8;   // == j*64 + c*8
      float4 a0 = *(const float4*)s;
      float4 a1 = *(const float4*)(s + 4);
      f16x8 o;
      o[0] = (f16)a0.x; o[1] = (f16)a0.y; o[2] = (f16)a0.z; o[3] = (f16)a0.w;
      o[4] = (f16)a1.x; o[5] = (f16)a1.y; o[6] = (f16)a1.z; o[7] = (f16)a1.w;
      const int cK    = (j >> 4) * 2 + (c >> 2);
      const int lanei = (c & 3) * 16 + (j & 15);
      *(f16x8*)(dst + (cK * 64 + lanei) * 8) = o;
    }
  } else {
    __shared__ float ldsv[64 * 68];    // [j][d], pad 68 keeps alignment
    const float* src = vg + base;
#pragma unroll
    for (int i = 0; i < 4; ++i) {
      const int row = t >> 2, col = (t & 3) * 16 + i * 4;
      *(float4*)&ldsv[row * 68 + col] = *(const float4*)(src + row * 64 + col);
    }
    __syncthreads();
    f16* dst = vp + base;
    const int d0 = (t >> 3) * 2;       // even d of the pair
    const int cl = t & 7;              // j-chunk
    f16x8 o0, o1;
#pragma unroll
    for (int s = 0; s < 8; ++s) {
      const int j = (cl & 1) * 32 + (s >> 2) * 16 + ((cl >> 1) & 3) * 4 + (s & 3);
      const float2 v2 = *(const float2*)&ldsv[j * 68 + d0];   // 8B-aligned
      o0[s] = (f16)v2.x; o1[s] = (f16)v2.y;
    }
    {
      const int cV0 = (d0 >> 4) * 2 + (cl & 1);
      const int li0 = (cl >> 1) * 16 + (d0 & 15);
      *(f16x8*)(dst + (cV0 * 64 + li0) * 8) = o0;
      const int d1 = d0 + 1;
      const int cV1 = (d1 >> 4) * 2 + (cl & 1);
      const int li1 = (cl >> 1) * 16 + (d1 & 15);
      *(f16x8*)(dst + (cV1 * 64 + li1) * 8) = o1;
    }
  }
}

// ====================== main kernel (r13 exact: ZERO LDS, 54.4us) =========
// r14 post-mortem: V double-buffer + early issue REGRESSED (54.4 -> 64.1us,
// VGPR 76 -> 100): clustering 16 loads + 3 live fragment sets broke the
// compiler's natural two-window pipelining (K issued after QK, V after PV).
// r15 reverts to the measured-best r13 structure verbatim.
__global__ __launch_bounds__(256, 2)
void attn_pp(const float* __restrict__ qg, const f16* __restrict__ kp,
             const f16* __restrict__ vp, float* __restrict__ og) {
  // head-clustered XCD swizzle (r3): each XCD owns 4 whole heads
  const int xcd  = blockIdx.x & 7;
  const int slot = blockIdx.x >> 3;
  const int bh   = xcd * 4 + (slot >> 4);
  const int qt   = slot & 15;
  const size_t hbase = (size_t)bh * S_LEN * D_DIM;
  const float* qh = qg + hbase;
  const f16*   kh = kp + hbase;
  const f16*   vh = vp + hbase;
  float*       oh = og + hbase;

  const int tid  = threadIdx.x;
  const int wave = tid >> 6;
  const int lane = tid & 63;
  const int L    = lane & 15;
  const int quad = lane >> 4;

  // ---- Q fragments, pre-scaled by SCALE_LOG2E (r12) ----
  f16x8 qf[2][2];
  const int qrow0 = qt * 128 + wave * 32;
#pragma unroll
  for (int qs = 0; qs < 2; ++qs)
#pragma unroll
    for (int kc = 0; kc < 2; ++kc) {
      const float* src = qh + (size_t)(qrow0 + qs * 16 + L) * D_DIM + kc * 32 + quad * 8;
      float4 x0 = *(const float4*)src;
      float4 x1 = *(const float4*)(src + 4);
      f16x8 t;
      t[0] = (f16)(x0.x * SCALE_LOG2E); t[1] = (f16)(x0.y * SCALE_LOG2E);
      t[2] = (f16)(x0.z * SCALE_LOG2E); t[3] = (f16)(x0.w * SCALE_LOG2E);
      t[4] = (f16)(x1.x * SCALE_LOG2E); t[5] = (f16)(x1.y * SCALE_LOG2E);
      t[6] = (f16)(x1.z * SCALE_LOG2E); t[7] = (f16)(x1.w * SCALE_LOG2E);
      qf[qs][kc] = t;
    }

  f32x4 oacc[2][4];
#pragma unroll
  for (int qs = 0; qs < 2; ++qs)
#pragma unroll
    for (int dt = 0; dt < 4; ++dt) oacc[qs][dt] = (f32x4){0.f, 0.f, 0.f, 0.f};
  float lsum[2] = {0.f, 0.f};

  // ---- fragment loads: 8 coalesced 16B/lane dwordx4 per operand per tile --
  f16x8 kf[8], vf[8];
#define LOADK(t_)                                                          \
  do {                                                                     \
    const f16* p = kh + (size_t)(t_) * 4096 + lane * 8;                    \
    _Pragma("unroll")                                                      \
    for (int c = 0; c < 8; ++c) kf[c] = *(const f16x8*)(p + c * 512);      \
  } while (0)
#define LOADV(t_)                                                          \
  do {                                                                     \
    const f16* p = vh + (size_t)(t_) * 4096 + lane * 8;                    \
    _Pragma("unroll")                                                      \
    for (int c = 0; c < 8; ++c) vf[c] = *(const f16x8*)(p + c * 512);      \
  } while (0)

  LOADK(0);
  LOADV(0);

  constexpr int NT = S_LEN / NTILE;
  for (int kt = 0; kt < NT; ++kt) {
    // ---- S^T = K Q^T : A = kf (reg), B = Q-frag (reg) ----
    f32x4 sfr[2][4];
#pragma unroll
    for (int qs = 0; qs < 2; ++qs)
#pragma unroll
      for (int jt = 0; jt < 4; ++jt) sfr[qs][jt] = (f32x4){0.f, 0.f, 0.f, 0.f};
#pragma unroll
    for (int jt = 0; jt < 4; ++jt)
#pragma unroll
      for (int kc = 0; kc < 2; ++kc) {
        const f16x8 af = kf[jt * 2 + kc];
        sfr[0][jt] = MFMA32(af, qf[0][kc], sfr[0][jt]);
        sfr[1][jt] = MFMA32(af, qf[1][kc], sfr[1][jt]);
      }

    // kf consumed -> issue next-tile K loads (land during exp2+PV+next wait)
    if (kt + 1 < NT) LOADK(kt + 1);

    // ---- softmax numerator: pf = f16(exp2(s)), lsum += sum(pf) ----
    f16x4 pf[2][4];
#pragma unroll
    for (int qs = 0; qs < 2; ++qs)
#pragma unroll
      for (int jt = 0; jt < 4; ++jt) {
#pragma unroll
        for (int r = 0; r < 4; ++r)
          pf[qs][jt][r] = (f16)__builtin_amdgcn_exp2f(sfr[qs][jt][r]);
#if __has_builtin(__builtin_amdgcn_fdot2)
        const f16x2 one2 = {(f16)1.f, (f16)1.f};
        f16x2 plo = {pf[qs][jt][0], pf[qs][jt][1]};
        f16x2 phi = {pf[qs][jt][2], pf[qs][jt][3]};
        lsum[qs] = __builtin_amdgcn_fdot2(plo, one2, lsum[qs], false);
        lsum[qs] = __builtin_amdgcn_fdot2(phi, one2, lsum[qs], false);
#else
#pragma unroll
        for (int r = 0; r < 4; ++r) lsum[qs] += (float)pf[qs][jt][r];
#endif
      }

    // ---- O += P V via 16x16x16: B = vf (reg, pre-permuted) ----
#pragma unroll
    for (int jtp = 0; jtp < 2; ++jtp)
#pragma unroll
      for (int dt = 0; dt < 4; ++dt) {
        const f16x8 vv = vf[dt * 2 + jtp];
        f16x4 vlo = {vv[0], vv[1], vv[2], vv[3]};
        f16x4 vhi = {vv[4], vv[5], vv[6], vv[7]};
        oacc[0][dt] = MFMA16(pf[0][jtp * 2],     vlo, oacc[0][dt]);
        oacc[0][dt] = MFMA16(pf[0][jtp * 2 + 1], vhi, oacc[0][dt]);
        oacc[1][dt] = MFMA16(pf[1][jtp * 2],     vlo, oacc[1][dt]);
        oacc[1][dt] = MFMA16(pf[1][jtp * 2 + 1], vhi, oacc[1][dt]);
      }

    // vf consumed -> issue next-tile V loads (land during next QK+exp2)
    if (kt + 1 < NT) LOADV(kt + 1);
  }
#undef LOADK
#undef LOADV

  // ---- epilogue: reduce l across quads, redistribute, store ----
#pragma unroll
  for (int qs = 0; qs < 2; ++qs) {
    float l = lsum[qs];
    l += __shfl_xor(l, 16);
    l += __shfl_xor(l, 32);
#pragma unroll
    for (int r = 0; r < 4; ++r) {
      const float inv = 1.0f / __shfl(l, quad * 4 + r);
      float* dst = oh + (size_t)(qrow0 + qs * 16 + quad * 4 + r) * D_DIM + L;
#pragma unroll
      for (int dt = 0; dt < 4; ++dt)
        dst[dt * 16] = oacc[qs][dt][r] * inv;
    }
  }
}

// ================= fallback: r7 kernel (no workspace needed) ==============
static constexpr int MBLOCK = 128;
static constexpr int KST = 72;
static constexpr int VST = 72;
static constexpr float FB_SCALE_LOG2E = 0.1803368801111204f;
static constexpr float FB_SHIFT = 4.0f;

__global__ __launch_bounds__(256, 2)
void attn_fwd_fb(const float* __restrict__ qg, const float* __restrict__ kg,
                 const float* __restrict__ vg, float* __restrict__ og) {
  const int xcd  = blockIdx.x & 7;
  const int slot = blockIdx.x >> 3;
  const int bh   = xcd * 4 + (slot >> 4);
  const int qt   = slot & 15;
  const size_t hbase = (size_t)bh * S_LEN * D_DIM;
  const float* qh = qg + hbase;
  const float* kh = kg + hbase;
  const float* vh = vg + hbase;
  float*       oh = og + hbase;

  const int tid  = threadIdx.x;
  const int wave = tid >> 6;
  const int lane = tid & 63;
  const int L    = lane & 15;
  const int quad = lane >> 4;
  const int lhalf = L >> 3;

  __shared__ f16 Ks[2][NTILE * KST];
  __shared__ f16 Vt[2][D_DIM * VST];

  f16x8 qf[2][2];
  const int qrow0 = qt * MBLOCK + wave * 32;
#pragma unroll
  for (int qs = 0; qs < 2; ++qs)
#pragma unroll
    for (int kc = 0; kc < 2; ++kc) {
      const float* src = qh + (size_t)(qrow0 + qs * 16 + L) * D_DIM + kc * 32 + quad * 8;
      float4 x0 = *(const float4*)src;
      float4 x1 = *(const float4*)(src + 4);
      f16x8 t;
      t[0] = (f16)x0.x; t[1] = (f16)x0.y; t[2] = (f16)x0.z; t[3] = (f16)x0.w;
      t[4] = (f16)x1.x; t[5] = (f16)x1.y; t[6] = (f16)x1.z; t[7] = (f16)x1.w;
      qf[qs][kc] = t;
    }

  f32x4 oacc[2][4];
#pragma unroll
  for (int qs = 0; qs < 2; ++qs)
#pragma unroll
    for (int dt = 0; dt < 4; ++dt) oacc[qs][dt] = (f32x4){0.f, 0.f, 0.f, 0.f};
  float lsum[2] = {0.f, 0.f};

  const int sj  = tid >> 2, sc  = tid & 3;
  const int jd  = tid >> 4, dcc = tid & 15;
  const int vpos = ((jd & 3) * 4 + (jd >> 2)) * 4;
  const int xorv = (dcc >> 1) << 3;
  const float* kstage = kh + (size_t)sj * D_DIM + sc * 4;
  const float* vstage = vh + (size_t)(jd * 4) * D_DIM + dcc * 4;

  float4 kreg[4], vreg[4];
#pragma unroll
  for (int i = 0; i < 4; ++i) {
    kreg[i] = *(const float4*)(kstage + i * 16);
    vreg[i] = *(const float4*)(vstage + (size_t)i * D_DIM);
  }
#pragma unroll
  for (int i = 0; i < 4; ++i) {
    f16x4 t;
    t[0] = (f16)kreg[i].x; t[1] = (f16)kreg[i].y;
    t[2] = (f16)kreg[i].z; t[3] = (f16)kreg[i].w;
    *(f16x4*)&Ks[0][sj * KST + i * 16 + sc * 4] = t;
  }
  {
    const float* vr = reinterpret_cast<const float*>(vreg);
#pragma unroll
    for (int c = 0; c < 4; ++c) {
      f16x4 t;
      t[0] = (f16)vr[0 * 4 + c]; t[1] = (f16)vr[1 * 4 + c];
      t[2] = (f16)vr[2 * 4 + c]; t[3] = (f16)vr[3 * 4 + c];
      *(f16x4*)&Vt[0][(dcc * 4 + c) * VST + (vpos ^ xorv)] = t;
    }
  }
#pragma unroll
  for (int i = 0; i < 4; ++i) {
    kreg[i] = *(const float4*)(kstage + (size_t)1 * NTILE * D_DIM + i * 16);
    vreg[i] = *(const float4*)(vstage + (size_t)1 * NTILE * D_DIM + (size_t)i * D_DIM);
  }
  __syncthreads();

  constexpr int NT = S_LEN / NTILE;
  for (int kt = 0; kt < NT; ++kt) {
    const int cur = kt & 1;
    const int nxt = cur ^ 1;

    f32x4 sfr[2][4];
#pragma unroll
    for (int qs = 0; qs < 2; ++qs)
#pragma unroll
      for (int jt = 0; jt < 4; ++jt) sfr[qs][jt] = (f32x4){0.f, 0.f, 0.f, 0.f};
#pragma unroll
    for (int jt = 0; jt < 4; ++jt)
#pragma unroll
      for (int kc = 0; kc < 2; ++kc) {
        f16x8 af = *(const f16x8*)&Ks[cur][(jt * 16 + L) * KST + kc * 32 + quad * 8];
        sfr[0][jt] = MFMA32(af, qf[0][kc], sfr[0][jt]);
        sfr[1][jt] = MFMA32(af, qf[1][kc], sfr[1][jt]);
      }

    if (kt + 1 < NT) {
#pragma unroll
      for (int i = 0; i < 4; ++i) {
        f16x4 t;
        t[0] = (f16)kreg[i].x; t[1] = (f16)kreg[i].y;
        t[2] = (f16)kreg[i].z; t[3] = (f16)kreg[i].w;
        *(f16x4*)&Ks[nxt][sj * KST + i * 16 + sc * 4] = t;
      }
      const float* vr = reinterpret_cast<const float*>(vreg);
#pragma unroll
      for (int c = 0; c < 4; ++c) {
        f16x4 t;
        t[0] = (f16)vr[0 * 4 + c]; t[1] = (f16)vr[1 * 4 + c];
        t[2] = (f16)vr[2 * 4 + c]; t[3] = (f16)vr[3 * 4 + c];
        *(f16x4*)&Vt[nxt][(dcc * 4 + c) * VST + (vpos ^ xorv)] = t;
      }
    }
    if (kt + 2 < NT) {
      const float* kpp = kstage + (size_t)(kt + 2) * NTILE * D_DIM;
      const float* vpp = vstage + (size_t)(kt + 2) * NTILE * D_DIM;
#pragma unroll
      for (int i = 0; i < 4; ++i) {
        kreg[i] = *(const float4*)(kpp + i * 16);
        vreg[i] = *(const float4*)(vpp + (size_t)i * D_DIM);
      }
    }

    f16x4 pf[2][4];
#pragma unroll
    for (int qs = 0; qs < 2; ++qs)
#pragma unroll
      for (int jt = 0; jt < 4; ++jt) {
#pragma unroll
        for (int r = 0; r < 4; ++r) {
          const float p = __builtin_amdgcn_exp2f(
              __builtin_fmaf(sfr[qs][jt][r], FB_SCALE_LOG2E, -FB_SHIFT));
          lsum[qs] += p;
          pf[qs][jt][r] = (f16)p;
        }
      }

#pragma unroll
    for (int jtp = 0; jtp < 2; ++jtp)
#pragma unroll
      for (int dt = 0; dt < 4; ++dt) {
        const int xorr = ((2 * dt + lhalf) & 7) << 3;
        f16x8 vf = *(const f16x8*)&Vt[cur][(dt * 16 + L) * VST +
                                          ((quad * 16 + jtp * 8) ^ xorr)];
        f16x4 vlo = {vf[0], vf[1], vf[2], vf[3]};
        f16x4 vhi = {vf[4], vf[5], vf[6], vf[7]};
        oacc[0][dt] = MFMA16(pf[0][jtp * 2],     vlo, oacc[0][dt]);
        oacc[0][dt] = MFMA16(pf[0][jtp * 2 + 1], vhi, oacc[0][dt]);
        oacc[1][dt] = MFMA16(pf[1][jtp * 2],     vlo, oacc[1][dt]);
        oacc[1][dt] = MFMA16(pf[1][jtp * 2 + 1], vhi, oacc[1][dt]);
      }

    __syncthreads();
  }

#pragma unroll
  for (int qs = 0; qs < 2; ++qs) {
    float l = lsum[qs];
    l += __shfl_xor(l, 16);
    l += __shfl_xor(l, 32);
#pragma unroll
    for (int r = 0; r < 4; ++r) {
      const float inv = 1.0f / __shfl(l, quad * 4 + r);
      float* dst = oh + (size_t)(qrow0 + qs * 16 + quad * 4 + r) * D_DIM + L;
#pragma unroll
      for (int dt = 0; dt < 4; ++dt)
        dst[dt * 16] = oacc[qs][dt][r] * inv;
    }
  }
}

extern "C" void kernel_launch(void* const* d_in, const int* in_sizes, int n_in,
                              void* d_out, int out_size, void* d_ws, size_t ws_size,
                              hipStream_t stream) {
  const float* q = (const float*)d_in[0];
  const float* k = (const float*)d_in[1];
  const float* v = (const float*)d_in[2];
  float* o = (float*)d_out;

  const size_t kv_elems = (size_t)32 * S_LEN * D_DIM;       // 4.19e6 f16 each
  const size_t need = 2 * kv_elems * sizeof(f16);           // 16 MB

  if (ws_size >= need && d_ws != nullptr) {
    f16* kp = (f16*)d_ws;
    f16* vp = kp + kv_elems;
    prepack<<<dim3(2048), dim3(256), 0, stream>>>(k, v, kp, vp);
    attn_pp<<<dim3(512), dim3(256), 0, stream>>>(q, kp, vp, o);
  } else {
    attn_fwd_fb<<<dim3(512), dim3(256), 0, stream>>>(q, k, v, o);
  }
}